// Round 3
// baseline (657.150 us; speedup 1.0000x reference)
//
#include <hip/hip_runtime.h>

// EETQLinear w8a16: out[m,n] = (sum_k x[m,k] * wq[k,n]) * scale[n] + bias[n]
// M=8192 (B*S), K=4096 (IN), N=4096 (OUT).
// HARNESS DTYPES (deduced r2): fp16 tensors arrive widened to FLOAT32
// (x, scale, bias = const float*; out = float*); int8 weight widened to int32.
// v3: fused, zero-workspace, reg-staged LDS, f16 MFMA (exact for fp16-origin data).

typedef __attribute__((ext_vector_type(4))) float     f32x4;
typedef __attribute__((ext_vector_type(8))) _Float16  f16x8;
typedef __attribute__((ext_vector_type(4))) _Float16  f16x4;

#define M_DIM 8192
#define N_DIM 4096
#define K_DIM 4096

#define BM 128
#define BN 128
#define BK 32
#define SB 36   // Bs row stride (f16 elems): 32+4 pad spreads scatter writes across banks

__global__ __launch_bounds__(256) void gemm_w8a16_fused(const float* __restrict__ A,
                                                        const int*   __restrict__ wq,
                                                        const float* __restrict__ scale,
                                                        const float* __restrict__ bias,
                                                        float*       __restrict__ C) {
    __shared__ __attribute__((aligned(16))) _Float16 As[BM * BK];  // [m][k], 8 KB
    __shared__ __attribute__((aligned(16))) _Float16 Bs[BN * SB];  // [n][k], 9 KB

    // XCD-aware bijective swizzle (2048 blocks, 2048 % 8 == 0)
    const int bid = blockIdx.x;
    const int swz = (bid & 7) * 256 + (bid >> 3);
    const int bm  = swz >> 5;            // 0..63  (M / BM)
    const int bn  = swz & 31;            // 0..31  (N / BN)

    const int t  = threadIdx.x;
    const int l  = t & 63;
    const int w  = t >> 6;
    const int wm = w >> 1, wn = w & 1;   // 2x2 wave grid, 64x64 output per wave
    const int lr = l & 15, lh = l >> 4;

    // A staging: thread t owns row t>>1, k-halves (t&1)*16 .. +15 (16 f32 per tile)
    const int ar = t >> 1, ak = (t & 1) * 16;
    const float* aSrc = A + (size_t)(bm * BM + ar) * K_DIM + ak;

    // B staging: thread t owns column nloc = t&127, k values (t>>7) + 2*i, i = 0..15
    const int nloc = t & 127;
    const int k0   = t >> 7;
    const int* bSrc = wq + (size_t)k0 * N_DIM + (size_t)bn * BN + nloc;

    f32x4 acc[4][4] = {};

    for (int kt = 0; kt < K_DIM; kt += BK) {
        // ---- global -> regs (before barrier: latency hides under prev tile's MFMA)
        float4 av[4];
        const float* ap_g = aSrc + kt;
#pragma unroll
        for (int j = 0; j < 4; ++j) av[j] = *(const float4*)(ap_g + 4 * j);
        int bw[16];
        const int* bp = bSrc + (size_t)kt * N_DIM;
#pragma unroll
        for (int i = 0; i < 16; ++i) bw[i] = bp[(size_t)(2 * i) * N_DIM];

        __syncthreads();                 // all waves done reading previous tiles

        // ---- regs -> LDS (convert f32/int -> f16; exact for fp16-origin / int8 data)
        f16x8 alo, ahi;
#pragma unroll
        for (int j = 0; j < 4; ++j) {
            alo[j]     = (_Float16)av[0][j];  alo[j + 4] = (_Float16)av[1][j];
            ahi[j]     = (_Float16)av[2][j];  ahi[j + 4] = (_Float16)av[3][j];
        }
        *(f16x8*)(As + ar * BK + ak)     = alo;
        *(f16x8*)(As + ar * BK + ak + 8) = ahi;
#pragma unroll
        for (int i = 0; i < 16; ++i)
            Bs[nloc * SB + k0 + 2 * i] = (_Float16)(float)bw[i];  // dequant-free int->f16
        __syncthreads();                 // tiles visible to all waves

        // ---- LDS -> fragments -> MFMA (layouts: m89/m92-verified, dtype-independent)
        f16x8 a[4], b[4];
        const _Float16* ap = As + (wm * 64 + lr) * BK + lh * 8;
#pragma unroll
        for (int mi = 0; mi < 4; ++mi) a[mi] = *(const f16x8*)(ap + mi * 16 * BK);
        const _Float16* bq = Bs + (wn * 64 + lr) * SB + lh * 8;
#pragma unroll
        for (int ni = 0; ni < 4; ++ni) {
            f16x4 b0 = *(const f16x4*)(bq + ni * 16 * SB);      // 8B-aligned (SB*2 = 72)
            f16x4 b1 = *(const f16x4*)(bq + ni * 16 * SB + 4);
            b[ni] = __builtin_shufflevector(b0, b1, 0, 1, 2, 3, 4, 5, 6, 7);
        }
#pragma unroll
        for (int mi = 0; mi < 4; ++mi)
#pragma unroll
            for (int ni = 0; ni < 4; ++ni)
                acc[mi][ni] = __builtin_amdgcn_mfma_f32_16x16x32_f16(a[mi], b[ni],
                                                                     acc[mi][ni], 0, 0, 0);
    }

    // epilogue: C/D layout col = lane&15, row = (lane>>4)*4 + reg  [m89-verified]
    const int col0 = bn * BN + wn * 64 + lr;
    const int row0 = bm * BM + wm * 64 + lh * 4;
    float sc[4], bi[4];
#pragma unroll
    for (int ni = 0; ni < 4; ++ni) {
        sc[ni] = scale[col0 + ni * 16];
        bi[ni] = bias[col0 + ni * 16];
    }
#pragma unroll
    for (int mi = 0; mi < 4; ++mi)
#pragma unroll
        for (int r = 0; r < 4; ++r) {
            const size_t rowOff = (size_t)(row0 + mi * 16 + r) * N_DIM;
#pragma unroll
            for (int ni = 0; ni < 4; ++ni)
                C[rowOff + col0 + ni * 16] = acc[mi][ni][r] * sc[ni] + bi[ni];
        }
}

extern "C" void kernel_launch(void* const* d_in, const int* in_sizes, int n_in,
                              void* d_out, int out_size, void* d_ws, size_t ws_size,
                              hipStream_t stream) {
    const float* x     = (const float*)d_in[0];  // [8192, 4096] f32 (fp16-origin)
    const int*   wq    = (const int*)d_in[1];    // [4096, 4096] int32 (int8 values)
    const float* scale = (const float*)d_in[2];  // [4096] f32
    const float* bias  = (const float*)d_in[3];  // [4096] f32
    float* out = (float*)d_out;                  // [8192, 4096] f32

    const int nblocks = (M_DIM / BM) * (N_DIM / BN);  // 2048
    gemm_w8a16_fused<<<nblocks, 256, 0, stream>>>(x, wq, scale, bias, out);
}

// Round 4
// 375.756 us; speedup vs baseline: 1.7489x; 1.7489x over previous
//
#include <hip/hip_runtime.h>

// EETQLinear w8a16: out[m,n] = (sum_k x[m,k] * wq[k,n]) * scale[n] + bias[n]
// M=8192 (B*S), K=4096 (IN), N=4096 (OUT).
// Harness dtypes (verified r3): x/scale/bias/out = float32; weight = int32 (int8 vals).
// v4: stage Wt f16 [N][K] (+ Xh f16) in d_ws once, then m97-structure MFMA GEMM
//     (128x128 tile, BK=32, global_load_lds 16B, 2 barriers). Tiered on ws_size.

typedef __attribute__((ext_vector_type(4))) float     f32x4;
typedef __attribute__((ext_vector_type(8))) _Float16  f16x8;
typedef __attribute__((ext_vector_type(4))) _Float16  f16x4;

#define M_DIM 8192
#define N_DIM 4096
#define K_DIM 4096

#define BM 128
#define BN 128
#define BK 32

// ---------------- x f32 [M*K] -> Xh f16, flat convert ----------------
__global__ __launch_bounds__(256) void convert_x_to_f16(const float* __restrict__ x,
                                                        _Float16* __restrict__ Xh) {
    const size_t i = ((size_t)blockIdx.x * 256 + threadIdx.x) * 8;
    float4 v0 = *(const float4*)(x + i);
    float4 v1 = *(const float4*)(x + i + 4);
    f16x8 h;
    h[0] = (_Float16)v0.x; h[1] = (_Float16)v0.y; h[2] = (_Float16)v0.z; h[3] = (_Float16)v0.w;
    h[4] = (_Float16)v1.x; h[5] = (_Float16)v1.y; h[6] = (_Float16)v1.z; h[7] = (_Float16)v1.w;
    *(f16x8*)(Xh + i) = h;
}

// ---------------- wq int32 [K][N] -> Wt f16 [N][K] (transpose + narrow) ----------------
__global__ __launch_bounds__(256) void dequant_w_to_f16(const int* __restrict__ wq,
                                                        _Float16* __restrict__ Wt) {
    __shared__ _Float16 tile[64][65];   // +1 pad: odd dword stride, conflict-free
    const int n0 = blockIdx.x * 64;
    const int k0 = blockIdx.y * 64;
    const int t  = threadIdx.x;

    const int r  = t >> 2;              // k within tile
    const int c0 = (t & 3) * 16;        // n within tile
    const int* src = wq + (size_t)(k0 + r) * N_DIM + n0 + c0;
#pragma unroll
    for (int j = 0; j < 4; ++j) {
        int4 q = *(const int4*)(src + j * 4);
        tile[c0 + j * 4 + 0][r] = (_Float16)q.x;
        tile[c0 + j * 4 + 1][r] = (_Float16)q.y;
        tile[c0 + j * 4 + 2][r] = (_Float16)q.z;
        tile[c0 + j * 4 + 3][r] = (_Float16)q.w;
    }
    __syncthreads();

    const int nn  = t >> 2;             // n within tile
    const int cc0 = (t & 3) * 16;       // k within tile
    _Float16 vals[16] __attribute__((aligned(16)));
#pragma unroll
    for (int j = 0; j < 16; ++j) vals[j] = tile[nn][cc0 + j];
    _Float16* dst = Wt + (size_t)(n0 + nn) * K_DIM + k0 + cc0;
    *(float4*)(dst + 0) = *(const float4*)(vals + 0);
    *(float4*)(dst + 8) = *(const float4*)(vals + 8);
}

// ---------------- GEMM, m97 structure ----------------
// MODE 0: A from Xh f16 via global_load_lds. MODE 1: A from x f32, reg-staged + cvt.
template <int MODE>
__global__ __launch_bounds__(256) void gemm_f16_ws(const float* __restrict__ Af32,
                                                   const _Float16* __restrict__ Ah,
                                                   const _Float16* __restrict__ Wt,
                                                   const float* __restrict__ scale,
                                                   const float* __restrict__ bias,
                                                   float* __restrict__ C) {
    __shared__ __attribute__((aligned(16))) _Float16 As[BM * BK];  // [m][k], 8 KB
    __shared__ __attribute__((aligned(16))) _Float16 Bs[BN * BK];  // [n][k], 8 KB

    // XCD-aware bijective swizzle (2048 blocks, 2048 % 8 == 0)
    const int bid = blockIdx.x;
    const int swz = (bid & 7) * 256 + (bid >> 3);
    const int bm  = swz >> 5;            // 0..63
    const int bn  = swz & 31;            // 0..31

    const int t  = threadIdx.x;
    const int l  = t & 63;
    const int w  = t >> 6;
    const int wm = w >> 1, wn = w & 1;   // 2x2 wave grid, 64x64 out per wave
    const int lr = l & 15, lh = l >> 4;

    f32x4 acc[4][4] = {};

    if (MODE == 0) {
        // thread t stages rows (t>>2) and (t>>2)+64, k-chunk (t&3)*8 (16 B)
        const _Float16* aSrc = Ah + (size_t)(bm * BM + (t >> 2)) * K_DIM + (t & 3) * 8;
        const _Float16* bSrc = Wt + (size_t)(bn * BN + (t >> 2)) * K_DIM + (t & 3) * 8;
        const size_t rowJump = (size_t)64 * K_DIM;
        char* asBase = (char*)As + t * 16;  // wave-uniform base + lane*16
        char* bsBase = (char*)Bs + t * 16;

        for (int kt = 0; kt < K_DIM; kt += BK) {
            __builtin_amdgcn_global_load_lds(
                (const __attribute__((address_space(1))) void*)(aSrc + kt),
                (__attribute__((address_space(3))) void*)(asBase), 16, 0, 0);
            __builtin_amdgcn_global_load_lds(
                (const __attribute__((address_space(1))) void*)(aSrc + rowJump + kt),
                (__attribute__((address_space(3))) void*)(asBase + 4096), 16, 0, 0);
            __builtin_amdgcn_global_load_lds(
                (const __attribute__((address_space(1))) void*)(bSrc + kt),
                (__attribute__((address_space(3))) void*)(bsBase), 16, 0, 0);
            __builtin_amdgcn_global_load_lds(
                (const __attribute__((address_space(1))) void*)(bSrc + rowJump + kt),
                (__attribute__((address_space(3))) void*)(bsBase + 4096), 16, 0, 0);
            __syncthreads();   // compiler drains vmcnt before barrier -> tiles ready

            f16x8 a[4], b[4];
            const _Float16* ap = As + (wm * 64 + lr) * BK + lh * 8;
            const _Float16* bp = Bs + (wn * 64 + lr) * BK + lh * 8;
#pragma unroll
            for (int mi = 0; mi < 4; ++mi) a[mi] = *(const f16x8*)(ap + mi * 16 * BK);
#pragma unroll
            for (int ni = 0; ni < 4; ++ni) b[ni] = *(const f16x8*)(bp + ni * 16 * BK);
#pragma unroll
            for (int mi = 0; mi < 4; ++mi)
#pragma unroll
                for (int ni = 0; ni < 4; ++ni)
                    acc[mi][ni] = __builtin_amdgcn_mfma_f32_16x16x32_f16(a[mi], b[ni],
                                                                         acc[mi][ni], 0, 0, 0);
            __syncthreads();   // all waves done reading before next stage overwrites
        }
    } else {
        // reg-staged: thread t owns row t>>1, k-chunk (t&1)*16 (16 elems) of each tile
        const int ar = t >> 1, ak = (t & 1) * 16;
        const float*    aSrc = Af32 + (size_t)(bm * BM + ar) * K_DIM + ak;
        const _Float16* bSrc = Wt   + (size_t)(bn * BN + ar) * K_DIM + ak;

        for (int kt = 0; kt < K_DIM; kt += BK) {
            float4 av[4];
#pragma unroll
            for (int j = 0; j < 4; ++j) av[j] = *(const float4*)(aSrc + kt + 4 * j);
            f16x8 bv0 = *(const f16x8*)(bSrc + kt);
            f16x8 bv1 = *(const f16x8*)(bSrc + kt + 8);

            __syncthreads();               // all waves done with previous tiles
            f16x8 alo, ahi;
#pragma unroll
            for (int j = 0; j < 4; ++j) {
                alo[j] = (_Float16)av[0][j];  alo[j + 4] = (_Float16)av[1][j];
                ahi[j] = (_Float16)av[2][j];  ahi[j + 4] = (_Float16)av[3][j];
            }
            *(f16x8*)(As + ar * BK + ak)     = alo;
            *(f16x8*)(As + ar * BK + ak + 8) = ahi;
            *(f16x8*)(Bs + ar * BK + ak)     = bv0;
            *(f16x8*)(Bs + ar * BK + ak + 8) = bv1;
            __syncthreads();               // tiles visible

            f16x8 a[4], b[4];
            const _Float16* ap = As + (wm * 64 + lr) * BK + lh * 8;
            const _Float16* bp = Bs + (wn * 64 + lr) * BK + lh * 8;
#pragma unroll
            for (int mi = 0; mi < 4; ++mi) a[mi] = *(const f16x8*)(ap + mi * 16 * BK);
#pragma unroll
            for (int ni = 0; ni < 4; ++ni) b[ni] = *(const f16x8*)(bp + ni * 16 * BK);
#pragma unroll
            for (int mi = 0; mi < 4; ++mi)
#pragma unroll
                for (int ni = 0; ni < 4; ++ni)
                    acc[mi][ni] = __builtin_amdgcn_mfma_f32_16x16x32_f16(a[mi], b[ni],
                                                                         acc[mi][ni], 0, 0, 0);
        }
    }

    // epilogue: C/D layout col = lane&15, row = (lane>>4)*4 + reg  [m89-verified]
    const int col0 = bn * BN + wn * 64 + lr;
    const int row0 = bm * BM + wm * 64 + lh * 4;
    float sc[4], bi[4];
#pragma unroll
    for (int ni = 0; ni < 4; ++ni) {
        sc[ni] = scale[col0 + ni * 16];
        bi[ni] = bias[col0 + ni * 16];
    }
#pragma unroll
    for (int mi = 0; mi < 4; ++mi)
#pragma unroll
        for (int r = 0; r < 4; ++r) {
            const size_t rowOff = (size_t)(row0 + mi * 16 + r) * N_DIM;
#pragma unroll
            for (int ni = 0; ni < 4; ++ni)
                C[rowOff + col0 + ni * 16] = acc[mi][ni][r] * sc[ni] + bi[ni];
        }
}

// ---------------- fallback (r3, known-pass): fully fused, zero workspace ----------------
#define SB 36
__global__ __launch_bounds__(256) void gemm_w8a16_fused(const float* __restrict__ A,
                                                        const int*   __restrict__ wq,
                                                        const float* __restrict__ scale,
                                                        const float* __restrict__ bias,
                                                        float*       __restrict__ C) {
    __shared__ __attribute__((aligned(16))) _Float16 As[BM * BK];
    __shared__ __attribute__((aligned(16))) _Float16 Bs[BN * SB];

    const int bid = blockIdx.x;
    const int swz = (bid & 7) * 256 + (bid >> 3);
    const int bm  = swz >> 5;
    const int bn  = swz & 31;

    const int t  = threadIdx.x;
    const int l  = t & 63;
    const int w  = t >> 6;
    const int wm = w >> 1, wn = w & 1;
    const int lr = l & 15, lh = l >> 4;

    const int ar = t >> 1, ak = (t & 1) * 16;
    const float* aSrc = A + (size_t)(bm * BM + ar) * K_DIM + ak;
    const int nloc = t & 127;
    const int k0   = t >> 7;
    const int* bSrc = wq + (size_t)k0 * N_DIM + (size_t)bn * BN + nloc;

    f32x4 acc[4][4] = {};

    for (int kt = 0; kt < K_DIM; kt += BK) {
        float4 av[4];
        const float* ap_g = aSrc + kt;
#pragma unroll
        for (int j = 0; j < 4; ++j) av[j] = *(const float4*)(ap_g + 4 * j);
        int bw[16];
        const int* bp = bSrc + (size_t)kt * N_DIM;
#pragma unroll
        for (int i = 0; i < 16; ++i) bw[i] = bp[(size_t)(2 * i) * N_DIM];

        __syncthreads();
        f16x8 alo, ahi;
#pragma unroll
        for (int j = 0; j < 4; ++j) {
            alo[j] = (_Float16)av[0][j];  alo[j + 4] = (_Float16)av[1][j];
            ahi[j] = (_Float16)av[2][j];  ahi[j + 4] = (_Float16)av[3][j];
        }
        *(f16x8*)(As + ar * BK + ak)     = alo;
        *(f16x8*)(As + ar * BK + ak + 8) = ahi;
#pragma unroll
        for (int i = 0; i < 16; ++i)
            Bs[nloc * SB + k0 + 2 * i] = (_Float16)(float)bw[i];
        __syncthreads();

        f16x8 a[4], b[4];
        const _Float16* ap = As + (wm * 64 + lr) * BK + lh * 8;
#pragma unroll
        for (int mi = 0; mi < 4; ++mi) a[mi] = *(const f16x8*)(ap + mi * 16 * BK);
        const _Float16* bq = Bs + (wn * 64 + lr) * SB + lh * 8;
#pragma unroll
        for (int ni = 0; ni < 4; ++ni) {
            f16x4 b0 = *(const f16x4*)(bq + ni * 16 * SB);
            f16x4 b1 = *(const f16x4*)(bq + ni * 16 * SB + 4);
            b[ni] = __builtin_shufflevector(b0, b1, 0, 1, 2, 3, 4, 5, 6, 7);
        }
#pragma unroll
        for (int mi = 0; mi < 4; ++mi)
#pragma unroll
            for (int ni = 0; ni < 4; ++ni)
                acc[mi][ni] = __builtin_amdgcn_mfma_f32_16x16x32_f16(a[mi], b[ni],
                                                                     acc[mi][ni], 0, 0, 0);
    }

    const int col0 = bn * BN + wn * 64 + lr;
    const int row0 = bm * BM + wm * 64 + lh * 4;
    float sc[4], bi[4];
#pragma unroll
    for (int ni = 0; ni < 4; ++ni) {
        sc[ni] = scale[col0 + ni * 16];
        bi[ni] = bias[col0 + ni * 16];
    }
#pragma unroll
    for (int mi = 0; mi < 4; ++mi)
#pragma unroll
        for (int r = 0; r < 4; ++r) {
            const size_t rowOff = (size_t)(row0 + mi * 16 + r) * N_DIM;
#pragma unroll
            for (int ni = 0; ni < 4; ++ni)
                C[rowOff + col0 + ni * 16] = acc[mi][ni][r] * sc[ni] + bi[ni];
        }
}

extern "C" void kernel_launch(void* const* d_in, const int* in_sizes, int n_in,
                              void* d_out, int out_size, void* d_ws, size_t ws_size,
                              hipStream_t stream) {
    const float* x     = (const float*)d_in[0];  // [8192, 4096] f32 (fp16-origin)
    const int*   wq    = (const int*)d_in[1];    // [4096, 4096] int32 (int8 values)
    const float* scale = (const float*)d_in[2];  // [4096] f32
    const float* bias  = (const float*)d_in[3];  // [4096] f32
    float* out = (float*)d_out;                  // [8192, 4096] f32

    const size_t needW = (size_t)N_DIM * K_DIM * sizeof(_Float16);   // 33.5 MB
    const size_t needX = (size_t)M_DIM * K_DIM * sizeof(_Float16);   // 67.1 MB
    const int nblocks  = (M_DIM / BM) * (N_DIM / BN);                // 2048

    if (ws_size >= needW + needX) {
        _Float16* Wt = (_Float16*)d_ws;
        _Float16* Xh = (_Float16*)((char*)d_ws + needW);
        dim3 tgrid(N_DIM / 64, K_DIM / 64);
        dequant_w_to_f16<<<tgrid, 256, 0, stream>>>(wq, Wt);
        convert_x_to_f16<<<(M_DIM * (size_t)K_DIM) / (256 * 8), 256, 0, stream>>>(x, Xh);
        gemm_f16_ws<0><<<nblocks, 256, 0, stream>>>(x, Xh, Wt, scale, bias, out);
    } else if (ws_size >= needW) {
        _Float16* Wt = (_Float16*)d_ws;
        dim3 tgrid(N_DIM / 64, K_DIM / 64);
        dequant_w_to_f16<<<tgrid, 256, 0, stream>>>(wq, Wt);
        gemm_f16_ws<1><<<nblocks, 256, 0, stream>>>(x, (const _Float16*)nullptr, Wt,
                                                    scale, bias, out);
    } else {
        gemm_w8a16_fused<<<nblocks, 256, 0, stream>>>(x, wq, scale, bias, out);
    }
}

// Round 5
// 278.194 us; speedup vs baseline: 2.3622x; 1.3507x over previous
//
#include <hip/hip_runtime.h>
#include <stdint.h>

// EETQLinear w8a16: out[m,n] = (sum_k x[m,k]*wq[k,n]) * scale[n] + bias[n]
// M=8192, K=4096, N=4096. Dtypes (r3/r4-verified): x/scale/bias/out f32, wq int32.
// v5: prologue (Wt f16 [N][K], Xh f16) + 256x256 8-phase counted-vmcnt MFMA GEMM
//     (m201 template: T1 XCD-swizzle + T2 LDS XOR-swizzle + T3/T4 8-phase counted
//      vmcnt + T5 setprio). ws_size >= 100.7MB verified in r4.

typedef __attribute__((ext_vector_type(4))) float     f32x4;
typedef __attribute__((ext_vector_type(8))) _Float16  f16x8;

#define M_DIM 8192
#define N_DIM 4096
#define K_DIM 4096

// ---------------- prologue kernels (r4-verified) ----------------
__global__ __launch_bounds__(256) void convert_x_to_f16(const float* __restrict__ x,
                                                        _Float16* __restrict__ Xh) {
    const size_t i = ((size_t)blockIdx.x * 256 + threadIdx.x) * 8;
    float4 v0 = *(const float4*)(x + i);
    float4 v1 = *(const float4*)(x + i + 4);
    f16x8 h;
    h[0] = (_Float16)v0.x; h[1] = (_Float16)v0.y; h[2] = (_Float16)v0.z; h[3] = (_Float16)v0.w;
    h[4] = (_Float16)v1.x; h[5] = (_Float16)v1.y; h[6] = (_Float16)v1.z; h[7] = (_Float16)v1.w;
    *(f16x8*)(Xh + i) = h;
}

__global__ __launch_bounds__(256) void dequant_w_to_f16(const int* __restrict__ wq,
                                                        _Float16* __restrict__ Wt) {
    __shared__ _Float16 tile[64][65];
    const int n0 = blockIdx.x * 64;
    const int k0 = blockIdx.y * 64;
    const int t  = threadIdx.x;
    const int r  = t >> 2;
    const int c0 = (t & 3) * 16;
    const int* src = wq + (size_t)(k0 + r) * N_DIM + n0 + c0;
#pragma unroll
    for (int j = 0; j < 4; ++j) {
        int4 q = *(const int4*)(src + j * 4);
        tile[c0 + j * 4 + 0][r] = (_Float16)q.x;
        tile[c0 + j * 4 + 1][r] = (_Float16)q.y;
        tile[c0 + j * 4 + 2][r] = (_Float16)q.z;
        tile[c0 + j * 4 + 3][r] = (_Float16)q.w;
    }
    __syncthreads();
    const int nn  = t >> 2;
    const int cc0 = (t & 3) * 16;
    _Float16 vals[16] __attribute__((aligned(16)));
#pragma unroll
    for (int j = 0; j < 16; ++j) vals[j] = tile[nn][cc0 + j];
    _Float16* dst = Wt + (size_t)(n0 + nn) * K_DIM + k0 + cc0;
    *(float4*)(dst + 0) = *(const float4*)(vals + 0);
    *(float4*)(dst + 8) = *(const float4*)(vals + 8);
}

// ---------------- 8-phase 256x256 GEMM ----------------
#define AS1C(p) (const __attribute__((address_space(1))) void*)(p)
#define AS3C(p) (__attribute__((address_space(3))) void*)(p)

// half h of A/B tile `tile` -> linear LDS of array `arr` (dest linear; source
// global address pre-inverse-swizzled so swizzled reads see correct data)
#define STAGE_A(arr, h, tile) do {                                                    \
    __builtin_amdgcn_global_load_lds(                                                 \
        AS1C(aStageBase + (size_t)((h) * 128) * K_DIM + (tile) * 64),                 \
        AS3C((char*)(arr) + (h) * 16384 + t * 16), 16, 0, 0);                         \
    __builtin_amdgcn_global_load_lds(                                                 \
        AS1C(aStageBase + (size_t)((h) * 128 + 64) * K_DIM + (tile) * 64),            \
        AS3C((char*)(arr) + (h) * 16384 + 8192 + t * 16), 16, 0, 0);                  \
} while (0)

#define STAGE_B(arr, h, tile) do {                                                    \
    __builtin_amdgcn_global_load_lds(                                                 \
        AS1C(bStageBase + (size_t)((h) * 128) * K_DIM + (tile) * 64),                 \
        AS3C((char*)(arr) + (h) * 16384 + t * 16), 16, 0, 0);                         \
    __builtin_amdgcn_global_load_lds(                                                 \
        AS1C(bStageBase + (size_t)((h) * 128 + 64) * K_DIM + (tile) * 64),            \
        AS3C((char*)(arr) + (h) * 16384 + 8192 + t * 16), 16, 0, 0);                  \
} while (0)

#define DSR(dst, addr, IMM) \
    asm volatile("ds_read_b128 %0, %1 offset:%c2" : "=v"(dst) : "v"(addr), "i"(IMM))

#define DSRA(Q, A0, A1)                      \
    DSR(af[0][0], A0, (Q) * 4096);           \
    DSR(af[0][1], A1, (Q) * 4096);           \
    DSR(af[1][0], A0, (Q) * 4096 + 2048);    \
    DSR(af[1][1], A1, (Q) * 4096 + 2048)

#define DSRB(BA0, BA1)                       \
    DSR(bf[0][0], BA0, 0);    DSR(bf[0][1], BA1, 0);    \
    DSR(bf[1][0], BA0, 2048); DSR(bf[1][1], BA1, 2048); \
    DSR(bf[2][0], BA0, 4096); DSR(bf[2][1], BA1, 4096); \
    DSR(bf[3][0], BA0, 6144); DSR(bf[3][1], BA1, 6144)

#define MM(AI, N)                                                                     \
    acc[AI][N] = __builtin_amdgcn_mfma_f32_16x16x32_f16(af[(AI) & 1][0], bf[N][0],    \
                                                        acc[AI][N], 0, 0, 0);         \
    acc[AI][N] = __builtin_amdgcn_mfma_f32_16x16x32_f16(af[(AI) & 1][1], bf[N][1],    \
                                                        acc[AI][N], 0, 0, 0)

#define MFMA16(Q)                                                     \
    MM((Q) * 2 + 0, 0); MM((Q) * 2 + 0, 1);                           \
    MM((Q) * 2 + 0, 2); MM((Q) * 2 + 0, 3);                           \
    MM((Q) * 2 + 1, 0); MM((Q) * 2 + 1, 1);                           \
    MM((Q) * 2 + 1, 2); MM((Q) * 2 + 1, 3)

#define BARR()  __builtin_amdgcn_s_barrier()
#define LGKM0() do { asm volatile("s_waitcnt lgkmcnt(0)" ::: "memory");               \
                     __builtin_amdgcn_sched_barrier(0); } while (0)
#define VMC2()  asm volatile("s_waitcnt vmcnt(2)" ::: "memory")
#define PRIO1() __builtin_amdgcn_s_setprio(1)
#define PRIO0() __builtin_amdgcn_s_setprio(0)

__global__ __launch_bounds__(512, 2) void gemm_8phase(const _Float16* __restrict__ Xh,
                                                      const _Float16* __restrict__ Wt,
                                                      const float* __restrict__ scale,
                                                      const float* __restrict__ bias,
                                                      float* __restrict__ C) {
    // 4 separate arrays: alias-clean for the compiler (no auto vmcnt drains)
    __shared__ __attribute__((aligned(128))) _Float16 As0_[16384];  // [256][64] f16
    __shared__ __attribute__((aligned(128))) _Float16 As1_[16384];
    __shared__ __attribute__((aligned(128))) _Float16 Bs0_[16384];
    __shared__ __attribute__((aligned(128))) _Float16 Bs1_[16384];

    // T1: XCD-aware bijective swizzle (512 blocks, 512 % 8 == 0)
    const int bid = blockIdx.x;
    const int swz = (bid & 7) * 64 + (bid >> 3);
    const int bm  = swz >> 4;            // 0..31
    const int bn  = swz & 15;            // 0..15

    const int t  = threadIdx.x;          // 0..511
    const int l  = t & 63;
    const int w  = t >> 6;               // 8 waves: 2(M) x 4(N)
    const int wm = w >> 2, wn = w & 3;   // wave block: 128 x 64
    const int lr = l & 15, lh = l >> 4;

    // staging: thread t covers row (t>>3)+{0,64} of each 128-row half, k-slot t&7.
    // T2 rule-21: linear LDS dest; SOURCE k pre-XORed by ((row&7)<<4) bytes.
    const int rowIdx = t >> 3;
    const int kbSw   = ((t & 7) * 16) ^ ((rowIdx & 7) << 4);
    const _Float16* aStageBase = Xh + (size_t)(bm * 256 + rowIdx) * K_DIM + (kbSw >> 1);
    const _Float16* bStageBase = Wt + (size_t)(bn * 256 + rowIdx) * K_DIM + (kbSw >> 1);

    // ds_read addresses (same XOR on the read side; bits 4-6 of base are clean
    // -> '+' == '|' for the kh/bit6 term)
    const int  mask = (lr & 7) << 4;
    const uint32_t m6   = (uint32_t)(mask & 64);
    const uint32_t aoff = (uint32_t)((wm * 128 + lr) * 128 + ((lh * 16) ^ (mask & 48)));
    const uint32_t boff = (uint32_t)((wn * 64 + lr) * 128 + ((lh * 16) ^ (mask & 48)));
    const uint32_t aA0k0 = (uint32_t)(uintptr_t)As0_ + aoff + m6;
    const uint32_t aA0k1 = (uint32_t)(uintptr_t)As0_ + aoff + (64u ^ m6);
    const uint32_t aA1k0 = (uint32_t)(uintptr_t)As1_ + aoff + m6;
    const uint32_t aA1k1 = (uint32_t)(uintptr_t)As1_ + aoff + (64u ^ m6);
    const uint32_t bB0k0 = (uint32_t)(uintptr_t)Bs0_ + boff + m6;
    const uint32_t bB0k1 = (uint32_t)(uintptr_t)Bs0_ + boff + (64u ^ m6);
    const uint32_t bB1k0 = (uint32_t)(uintptr_t)Bs1_ + boff + m6;
    const uint32_t bB1k1 = (uint32_t)(uintptr_t)Bs1_ + boff + (64u ^ m6);

    f16x8 af[2][2], bf[4][2];
    f32x4 acc[8][4] = {};

    // prologue: stage K-tile 0 into buf0 (8 loads/wave outstanding)
    STAGE_A(As0_, 0, 0); STAGE_A(As0_, 1, 0);
    STAGE_B(Bs0_, 0, 0); STAGE_B(Bs0_, 1, 0);

#pragma unroll 1
    for (int i = 0; i < K_DIM / 128; ++i) {       // 32 iters, 2 K-tiles each
        const int t1 = 2 * i + 1;                 // <= 63, no wrap
        const int t2 = (2 * i + 2) & 63;          // wraps only on last iter (unused data)
        // -- phase 0 (K-tile 2i, buf0, quadrant 0)
        STAGE_A(As1_, 0, t1);
        VMC2(); BARR();                           // buf0's 8 loads landed (all waves)
        DSRB(bB0k0, bB0k1);
        DSRA(0, aA0k0, aA0k1);
        LGKM0(); PRIO1(); MFMA16(0); PRIO0(); BARR();
        // -- phase 1
        DSRA(1, aA0k0, aA0k1);
        STAGE_A(As1_, 1, t1);
        BARR(); LGKM0(); PRIO1(); MFMA16(1); PRIO0(); BARR();
        // -- phase 2
        DSRA(2, aA0k0, aA0k1);
        STAGE_B(Bs1_, 0, t1);
        BARR(); LGKM0(); PRIO1(); MFMA16(2); PRIO0(); BARR();
        // -- phase 3
        DSRA(3, aA0k0, aA0k1);
        STAGE_B(Bs1_, 1, t1);
        BARR(); LGKM0(); PRIO1(); MFMA16(3); PRIO0(); BARR();
        // -- phase 4 (K-tile 2i+1, buf1, quadrant 0)
        STAGE_A(As0_, 0, t2);
        VMC2(); BARR();
        DSRB(bB1k0, bB1k1);
        DSRA(0, aA1k0, aA1k1);
        LGKM0(); PRIO1(); MFMA16(0); PRIO0(); BARR();
        // -- phase 5
        DSRA(1, aA1k0, aA1k1);
        STAGE_A(As0_, 1, t2);
        BARR(); LGKM0(); PRIO1(); MFMA16(1); PRIO0(); BARR();
        // -- phase 6
        DSRA(2, aA1k0, aA1k1);
        STAGE_B(Bs0_, 0, t2);
        BARR(); LGKM0(); PRIO1(); MFMA16(2); PRIO0(); BARR();
        // -- phase 7
        DSRA(3, aA1k0, aA1k1);
        STAGE_B(Bs0_, 1, t2);
        BARR(); LGKM0(); PRIO1(); MFMA16(3); PRIO0(); BARR();
    }
    asm volatile("s_waitcnt vmcnt(0)" ::: "memory");  // drain dangling prefetch

    // epilogue: C/D layout col = lane&15, row = (lane>>4)*4 + reg  [m89-verified]
    const int col0 = bn * 256 + wn * 64 + lr;
    const int row0 = bm * 256 + wm * 128 + lh * 4;
    float sc[4], bi[4];
#pragma unroll
    for (int ni = 0; ni < 4; ++ni) {
        sc[ni] = scale[col0 + ni * 16];
        bi[ni] = bias[col0 + ni * 16];
    }
#pragma unroll
    for (int ai = 0; ai < 8; ++ai)
#pragma unroll
        for (int r = 0; r < 4; ++r) {
            const size_t rowOff = (size_t)(row0 + ai * 16 + r) * N_DIM;
#pragma unroll
            for (int ni = 0; ni < 4; ++ni)
                C[rowOff + col0 + ni * 16] = acc[ai][ni][r] * sc[ni] + bi[ni];
        }
}

extern "C" void kernel_launch(void* const* d_in, const int* in_sizes, int n_in,
                              void* d_out, int out_size, void* d_ws, size_t ws_size,
                              hipStream_t stream) {
    const float* x     = (const float*)d_in[0];
    const int*   wq    = (const int*)d_in[1];
    const float* scale = (const float*)d_in[2];
    const float* bias  = (const float*)d_in[3];
    float* out = (float*)d_out;

    const size_t needW = (size_t)N_DIM * K_DIM * sizeof(_Float16);   // 33.5 MB
    _Float16* Wt = (_Float16*)d_ws;
    _Float16* Xh = (_Float16*)((char*)d_ws + needW);                 // ws >= 100.7MB (r4)

    dim3 tgrid(N_DIM / 64, K_DIM / 64);
    dequant_w_to_f16<<<tgrid, 256, 0, stream>>>(wq, Wt);
    convert_x_to_f16<<<((size_t)M_DIM * K_DIM) / (256 * 8), 256, 0, stream>>>(x, Xh);

    const int nblocks = (M_DIM / 256) * (N_DIM / 256);               // 512
    gemm_8phase<<<nblocks, 512, 0, stream>>>(Xh, Wt, scale, bias, out);
}